// Round 9
// baseline (92.073 us; speedup 1.0000x reference)
//
#include <hip/hip_runtime.h>

constexpr int FIELD = 26;
constexpr int EDIM  = 32;
constexpr int NPAIR = 325;   // C(26,2)
constexpr int BT    = 16;    // batch rows per block (one MFMA tile, one wave)
constexpr int PG    = 8;     // pairs per block -> 1 KB contiguous out run per row
constexpr int NGRP  = (NPAIR + PG - 1) / PG;   // 41 (last group: 5 pairs)

typedef __bf16 bf16x8 __attribute__((ext_vector_type(8)));
typedef float  f32x4  __attribute__((ext_vector_type(4)));

static __device__ inline bf16x8 cvt8(const float4 a, const float4 b) {
    bf16x8 r;
    r[0] = (__bf16)a.x; r[1] = (__bf16)a.y; r[2] = (__bf16)a.z; r[3] = (__bf16)a.w;
    r[4] = (__bf16)b.x; r[5] = (__bf16)b.y; r[6] = (__bf16)b.z; r[7] = (__bf16)b.w;
    return r;
}

__global__ __launch_bounds__(64) void bilinear_wavesweep(
    const float* __restrict__ x,     // [B][26][32]
    const float* __restrict__ W,     // [325][32][32]  W[p][e][d]
    const float* __restrict__ bias,  // [325][32]
    float* __restrict__ out)         // [B][325][32]
{
    // wave-private: [row][pair][f4col], f4col XOR-swizzled by row&7.  16 KB.
    __shared__ float4 stage[BT][PG][8];

    const int l  = threadIdx.x;      // single wave
    const int lr = l & 15;           // MFMA col = batch row in tile
    const int g  = l >> 4;           // k-group / e-quad group
    const int po = l >> 3;           // sweep: pair offset 0..7
    const int eq = l & 7;            // sweep: e-quad 0..7

    const int b0  = blockIdx.x * BT;           // bt fast: same-bt groups land on one XCD
    const int p0  = blockIdx.y * PG;
    const int cnt = min(PG, NPAIR - p0);

    const float* xrow = x + (size_t)(b0 + lr) * FIELD * EDIM;

    // decode triu pair p0 -> (fi, fj) once; walk incrementally per pair
    int fi = 0, rem = p0;
    #pragma unroll 1
    while (rem >= FIELD - 1 - fi) { rem -= FIELD - 1 - fi; ++fi; }
    int fj = fi + 1 + rem;

    for (int q = 0; q < cnt; ++q) {
        const int p = p0 + q;

        // xi fragment: x[b0+lr][fi][g*8 .. +7]
        const float* xp = xrow + fi * EDIM + g * 8;
        const bf16x8 xf = cvt8(*(const float4*)xp, *(const float4*)(xp + 4));

        #pragma unroll
        for (int n = 0; n < 2; ++n) {
            // W fragment: W[p][n*16+lr][g*8 .. +7]
            const float* wp = W + ((size_t)p * EDIM + n * 16 + lr) * EDIM + g * 8;
            const bf16x8 wf = cvt8(*(const float4*)wp, *(const float4*)(wp + 4));

            const f32x4 acc = __builtin_amdgcn_mfma_f32_16x16x32_bf16(
                wf, xf, (f32x4){0.f, 0.f, 0.f, 0.f}, 0, 0, 0);

            // lane holds D[e][b]: e = n*16 + g*4 + reg, b = b0 + lr
            const int e0 = n * 16 + g * 4;
            const float4 b4  = *(const float4*)(bias + (size_t)p * EDIM + e0);
            const float4 xj4 = *(const float4*)(xrow + fj * EDIM + e0);
            float4 r;
            r.x = (acc[0] + b4.x) * xj4.x;
            r.y = (acc[1] + b4.y) * xj4.y;
            r.z = (acc[2] + b4.z) * xj4.z;
            r.w = (acc[3] + b4.w) * xj4.w;

            // logical e-quad s = n*4+g stored at swizzled col s ^ (lr&7)
            stage[lr][q][(n * 4 + g) ^ (lr & 7)] = r;
        }

        // next pair (wave-uniform walk)
        if (++fj == FIELD) { ++fi; fj = fi + 1; }
    }

    // ---- store sweep: per row, ONE wave-instr writes 8 pairs * 128 B = 1 KB contiguous.
    // Same-wave cross-lane LDS: in-order DS pipeline, no barrier needed.
    #pragma unroll
    for (int row = 0; row < BT; ++row) {
        if (po < cnt) {
            const float4 v = stage[row][po][eq ^ (row & 7)];   // logical e-quad = eq
            *(float4*)(out + (((size_t)(b0 + row)) * NPAIR + p0 + po) * EDIM + eq * 4) = v;
        }
    }
}

extern "C" void kernel_launch(void* const* d_in, const int* in_sizes, int n_in,
                              void* d_out, int out_size, void* d_ws, size_t ws_size,
                              hipStream_t stream) {
    const float* x    = (const float*)d_in[0];
    const float* W    = (const float*)d_in[1];
    const float* bias = (const float*)d_in[2];
    float* out        = (float*)d_out;

    const int B = in_sizes[0] / (FIELD * EDIM);   // 4096
    dim3 grid(B / BT, NGRP);                       // (256, 41); bt stride 256 = 0 mod 8 XCDs
    bilinear_wavesweep<<<grid, dim3(64), 0, stream>>>(x, W, bias, out);
}

// Round 10
// 74.313 us; speedup vs baseline: 1.2390x; 1.2390x over previous
//
#include <hip/hip_runtime.h>

constexpr int FIELD = 26;
constexpr int EDIM  = 32;
constexpr int NPAIR = 325;   // C(26,2)
constexpr int BT    = 16;    // batch rows per wave-tile

typedef __bf16 bf16x8 __attribute__((ext_vector_type(8)));
typedef float  f32x4  __attribute__((ext_vector_type(4)));

static __device__ inline bf16x8 cvt8(const float4 a, const float4 b) {
    bf16x8 r;
    r[0] = (__bf16)a.x; r[1] = (__bf16)a.y; r[2] = (__bf16)a.z; r[3] = (__bf16)a.w;
    r[4] = (__bf16)b.x; r[5] = (__bf16)b.y; r[6] = (__bf16)b.z; r[7] = (__bf16)b.w;
    return r;
}

struct Frag {   // 9 float4 = 36 VGPR
    float4 xi0, xi1;           // xi fragment (lr/g mapping)
    float4 w0, w1, w2, w3;     // W[p][{0,16}+lr][g*8..+7]
    float4 b4;                 // bias[p][eq*4..+3]      (store-side mapping)
    float4 xj0, xj1;           // x[b0+bq(+8)][fj][eq*4] (store-side mapping)
};

__global__ __launch_bounds__(256, 4) void bilinear_pipe(
    const float* __restrict__ x,     // [B][26][32]
    const float* __restrict__ W,     // [325][32][32]
    const float* __restrict__ bias,  // [325][32]
    float* __restrict__ out,         // [B][325][32]
    int ntiles)                      // (B/BT)*NPAIR
{
    // wave-local transpose stages, double-buffered (A/B iterations)
    __shared__ float4 stage[4][2][BT][8];   // 16 KB

    const int tid = threadIdx.x;
    const int w   = tid >> 6;        // wave 0..3
    const int l   = tid & 63;
    const int lr  = l & 15;          // MFMA col = batch row in tile
    const int g   = l >> 4;          // k-group / e-quad group
    const int bq  = l >> 3;          // store phase: row base 0..7
    const int eq  = l & 7;           // store phase: e-quad 0..7

    auto load_tile = [&](int idx, Frag& f, int& p, int& b0) {
        const int bt = (int)(((unsigned long long)(unsigned)idx * 13215284ull) >> 32); // exact /325
        p  = idx - bt * NPAIR;
        b0 = bt * BT;
        // W + bias depend only on p: issue first
        const float* wp0 = W + ((size_t)p * EDIM + lr) * EDIM + g * 8;
        f.w0 = *(const float4*)wp0;
        f.w1 = *(const float4*)(wp0 + 4);
        const float* wp1 = wp0 + 16 * EDIM;
        f.w2 = *(const float4*)wp1;
        f.w3 = *(const float4*)(wp1 + 4);
        f.b4 = *(const float4*)(bias + (size_t)p * EDIM + eq * 4);
        // decode triu pair -> (fi, fj)
        int fi = 0, rem = p;
        #pragma unroll 1
        while (rem >= FIELD - 1 - fi) { rem -= FIELD - 1 - fi; ++fi; }
        const int fj = fi + 1 + rem;
        const float* xp = x + ((size_t)(b0 + lr) * FIELD + fi) * EDIM + g * 8;
        f.xi0 = *(const float4*)xp;
        f.xi1 = *(const float4*)(xp + 4);
        f.xj0 = *(const float4*)(x + ((size_t)(b0 + bq)     * FIELD + fj) * EDIM + eq * 4);
        f.xj1 = *(const float4*)(x + ((size_t)(b0 + bq + 8) * FIELD + fj) * EDIM + eq * 4);
    };

    auto compute_store = [&](const Frag& f, int p, int b0, float4 (*stg)[8]) {
        const bf16x8 xf = cvt8(f.xi0, f.xi1);
        const f32x4 zero = {0.f, 0.f, 0.f, 0.f};
        // D[e][b]: lane holds b = b0+lr, e = n*16 + g*4 + reg; logical col s = n*4+g (e0 = 4s)
        const f32x4 a0 = __builtin_amdgcn_mfma_f32_16x16x32_bf16(cvt8(f.w0, f.w1), xf, zero, 0, 0, 0);
        float4 v0; v0.x = a0[0]; v0.y = a0[1]; v0.z = a0[2]; v0.w = a0[3];
        stg[lr][g ^ (lr & 7)] = v0;
        const f32x4 a1 = __builtin_amdgcn_mfma_f32_16x16x32_bf16(cvt8(f.w2, f.w3), xf, zero, 0, 0, 0);
        float4 v1; v1.x = a1[0]; v1.y = a1[1]; v1.z = a1[2]; v1.w = a1[3];
        stg[lr][(4 + g) ^ (lr & 7)] = v1;
        // wave-local transpose read (in-order DS per wave; no barrier)
        const float4 t0 = stg[bq][eq ^ (bq & 7)];
        const float4 t1 = stg[bq + 8][eq ^ (bq & 7)];
        float4 r0, r1;
        r0.x = (t0.x + f.b4.x) * f.xj0.x;  r0.y = (t0.y + f.b4.y) * f.xj0.y;
        r0.z = (t0.z + f.b4.z) * f.xj0.z;  r0.w = (t0.w + f.b4.w) * f.xj0.w;
        r1.x = (t1.x + f.b4.x) * f.xj1.x;  r1.y = (t1.y + f.b4.y) * f.xj1.y;
        r1.z = (t1.z + f.b4.z) * f.xj1.z;  r1.w = (t1.w + f.b4.w) * f.xj1.w;
        *(float4*)(out + ((size_t)(b0 + bq)     * NPAIR + p) * EDIM + eq * 4) = r0;
        *(float4*)(out + ((size_t)(b0 + bq + 8) * NPAIR + p) * EDIM + eq * 4) = r1;
    };

    int idx = blockIdx.x * 4 + w;
    const int stride = gridDim.x * 4;
    if (idx >= ntiles) return;

    Frag A, B;
    int pA, b0A, pB, b0B;
    float4 (*stgA)[8] = stage[w][0];
    float4 (*stgB)[8] = stage[w][1];

    load_tile(idx, A, pA, b0A);
    for (;;) {
        const int i1 = idx + stride;
        if (i1 < ntiles) load_tile(i1, B, pB, b0B);   // prefetch issues before A's stores
        compute_store(A, pA, b0A, stgA);              // A's stores fly while B's loads land
        if (i1 >= ntiles) break;
        const int i2 = i1 + stride;
        if (i2 < ntiles) load_tile(i2, A, pA, b0A);
        compute_store(B, pB, b0B, stgB);
        if (i2 >= ntiles) break;
        idx = i2;
    }
}

extern "C" void kernel_launch(void* const* d_in, const int* in_sizes, int n_in,
                              void* d_out, int out_size, void* d_ws, size_t ws_size,
                              hipStream_t stream) {
    const float* x    = (const float*)d_in[0];
    const float* W    = (const float*)d_in[1];
    const float* bias = (const float*)d_in[2];
    float* out        = (float*)d_out;

    const int B      = in_sizes[0] / (FIELD * EDIM);   // 4096
    const int ntiles = (B / BT) * NPAIR;               // 83200
    bilinear_pipe<<<dim3(1024), dim3(256), 0, stream>>>(x, W, bias, out, ntiles);
}